// Round 1
// 623.581 us; speedup vs baseline: 1.0044x; 1.0044x over previous
//
#include <hip/hip_runtime.h>

#define N_ROWS 65536
#define DIM    512
#define K_CENT 4096
#define TILE_M 128
#define TILE_N 128
#define BK     64
#define KSTEPS (DIM / BK)        // 8
#define NKT    (K_CENT / TILE_N) // 32
#define NSTEP  (NKT * KSTEPS)    // 256
#define THREADS 512
#define MARGIN 22.0f
#define CAND_CAP 1536
#define COMPACT_TRIG 1024
#define SCALE1 0x7F7F7F7F        // e8m0 scale = 2^0 in every byte

typedef float  floatx4  __attribute__((ext_vector_type(4)));
typedef float  floatx16 __attribute__((ext_vector_type(16)));
typedef int    intx2    __attribute__((ext_vector_type(2)));
typedef int    intx4    __attribute__((ext_vector_type(4)));
typedef int    intx8    __attribute__((ext_vector_type(8)));

// order-preserving float<->uint map
__device__ __forceinline__ unsigned mapF(float f) {
  unsigned u = __float_as_uint(f);
  return (u & 0x80000000u) ? ~u : (u | 0x80000000u);
}
__device__ __forceinline__ float unmapF(unsigned m) {
  unsigned u = (m & 0x80000000u) ? (m ^ 0x80000000u) : ~m;
  return __uint_as_float(u);
}

__device__ __forceinline__ void gload_lds16(const void* g, void* l) {
  __builtin_amdgcn_global_load_lds(
      (const __attribute__((address_space(1))) void*)g,
      (__attribute__((address_space(3))) void*)l, 16, 0, 0);
}

// pack 4 floats -> 4 OCP e4m3 bytes
__device__ __forceinline__ int pk4(float a, float b, float c, float d) {
  int r = __builtin_amdgcn_cvt_pk_fp8_f32(a, b, 0, false);
  r = __builtin_amdgcn_cvt_pk_fp8_f32(c, d, r, true);
  return r;
}

// raw barrier with LDS visibility, NO vmcnt drain (prefetch stays in flight)
#define FENCE_BAR() do { asm volatile("s_waitcnt lgkmcnt(0)" ::: "memory"); \
                         __builtin_amdgcn_s_barrier();                       \
                         __builtin_amdgcn_sched_barrier(0); } while (0)

// fp32 -> fp8 for x and center (16 elems/thread); EXACT fp32 csq fused into center branch
__global__ void prep_convert(const float* __restrict__ x, const float* __restrict__ c,
                             unsigned char* __restrict__ xq, unsigned char* __restrict__ cq,
                             float* __restrict__ csqg) {
  const size_t nx = (size_t)N_ROWS * DIM;
  size_t i = ((size_t)blockIdx.x * blockDim.x + threadIdx.x) * 16;
  if (i < nx) {
    floatx4 a0 = *(const floatx4*)(x + i);
    floatx4 a1 = *(const floatx4*)(x + i + 4);
    floatx4 a2 = *(const floatx4*)(x + i + 8);
    floatx4 a3 = *(const floatx4*)(x + i + 12);
    intx4 q = { pk4(a0[0],a0[1],a0[2],a0[3]), pk4(a1[0],a1[1],a1[2],a1[3]),
                pk4(a2[0],a2[1],a2[2],a2[3]), pk4(a3[0],a3[1],a3[2],a3[3]) };
    *(intx4*)(xq + i) = q;
  } else if (i < nx + (size_t)K_CENT * DIM) {
    size_t off = i - nx;
    floatx4 a0 = *(const floatx4*)(c + off);
    floatx4 a1 = *(const floatx4*)(c + off + 4);
    floatx4 a2 = *(const floatx4*)(c + off + 8);
    floatx4 a3 = *(const floatx4*)(c + off + 12);
    intx4 q = { pk4(a0[0],a0[1],a0[2],a0[3]), pk4(a1[0],a1[1],a1[2],a1[3]),
                pk4(a2[0],a2[1],a2[2],a2[3]), pk4(a3[0],a3[1],a3[2],a3[3]) };
    *(intx4*)(cq + off) = q;
    float s = 0.f;
#pragma unroll
    for (int e = 0; e < 4; ++e)
      s += a0[e]*a0[e] + a1[e]*a1[e] + a2[e]*a2[e] + a3[e]*a3[e];
#pragma unroll
    for (int o = 1; o < 32; o <<= 1) s += __shfl_xor(s, o, 64);
    if ((threadIdx.x & 31) == 0) csqg[off >> 9] = s;  // 32 threads cover one 512-elem row
  }
}

// Pipelined main kernel (requires ws: fp8 x/c + exact fp32 csq).
//
// Structure (T3+T4 port, cf. 8-phase template): 3 x 8KB chunk buffers per
// operand, prefetch depth 2, raw s_barrier + counted "s_waitcnt vmcnt(4)"
// (never 0 inside the loop). csq staged to LDS once so the ONLY VMEM ops in
// the steady-state loop are the 2 counted global_load_lds per step ->
// vmcnt bookkeeping is exact (and conservative-correct even if scratch ops
// sneak in, since vmcnt retires in-order from the oldest).
// Per step: issue loads(j+2) -> vmcnt(4) [loads(j) done] -> barrier ->
// 6x ds_read_b128 -> lgkmcnt(0) -> 2x mfma_scale 32x32x64 -> close barrier
// (protects buf j%3 before loads(j+3) land, issued after it next step).
// __launch_bounds__(512,2): VGPR cap 128; anything in (64,128] still gives
// 4 waves/SIMD = 2 blocks/CU, which is all the grid (512 blocks) provides.
// LDS: 48K dyn (A/B rings) + 16K csq + ~14K cand/misc = 79.4K -> 2 blocks/CU.
__global__ __launch_bounds__(THREADS, 2)
void kmeans_argmin_pipe(const float* __restrict__ x, const float* __restrict__ cent,
                        const unsigned char* __restrict__ xq, const unsigned char* __restrict__ cq,
                        const float* __restrict__ csqg, int* __restrict__ out) {
  extern __shared__ __align__(16) unsigned char dynLds[];
  unsigned char* ldsA = dynLds;               // 3 * 8192
  unsigned char* ldsB = dynLds + 3 * 8192;    // 3 * 8192
  __shared__ float csqL[K_CENT];              // 16 KB
  __shared__ unsigned sminU[TILE_M];
  __shared__ unsigned long long best[TILE_M];
  __shared__ unsigned candKey[CAND_CAP];      // 6 KB
  __shared__ float candS[CAND_CAP];           // 6 KB
  __shared__ int candCount;

  const int t = threadIdx.x;
  const int lane = t & 63;
  const int wave = t >> 6;   // 0..7
  const int wm = wave >> 1;  // 0..3 row-waves (32 rows each)
  const int wn = wave & 1;   // 0..1 col-waves (64 cols each)
  const int l31 = lane & 31;
  const int half = lane >> 5;
  const int rowBlock = blockIdx.x * TILE_M;

  if (t < TILE_M) { sminU[t] = 0xFFFFFFFFu; best[t] = ~0ull; }
  if (t == 0) candCount = 0;
  for (int i = t; i < K_CENT; i += THREADS) csqL[i] = csqg[i];

  // staging slot decode (slot s=t -> row/chunk), same mapping as before
  const int rS = (t >> 2) & 31;
  const int rowS = (t >> 7) * 32 + rS;
  const int offS = (((t & 3) ^ ((rS >> 1) & 3)) << 4);
  // fragment read slots
  const int qk = half * 2;
  const int fragSlotBase = 4 * l31 + (qk ^ ((l31 >> 1) & 3)); // + group*128; pair = ^1

  const size_t aRowOff = (size_t)(rowBlock + rowS) * DIM + offS;

  // retire csq loads so loop vmcnt counting starts clean
  asm volatile("s_waitcnt vmcnt(0)" ::: "memory");
  // prologue prefetch: steps 0 and 1 into bufs 0 and 1
  gload_lds16(xq + aRowOff + 0,  ldsA + wave * 1024);
  gload_lds16(cq + (size_t)rowS * DIM + 0 + offS,  ldsB + wave * 1024);
  gload_lds16(xq + aRowOff + 64, ldsA + 8192 + wave * 1024);
  gload_lds16(cq + (size_t)rowS * DIM + 64 + offS, ldsB + 8192 + wave * 1024);
  FENCE_BAR();   // csqL/sminU init visible; prefetch stays in flight

  floatx16 acc[2];
#pragma unroll
  for (int fn = 0; fn < 2; ++fn)
#pragma unroll
    for (int e = 0; e < 16; ++e) acc[fn][e] = 0.f;

  int bi = 0;  // buffer of current step (j % 3)
  for (int j = 0; j < NSTEP; ++j) {
    const int kt = j >> 3, ks = j & 7;
    // ---- issue prefetch for step j+2, then wait for step j's loads ----
    if (j + 2 < NSTEP) {
      const int j2 = j + 2;
      const int kt2 = j2 >> 3, ks2 = j2 & 7;
      int b2 = bi + 2; if (b2 >= 3) b2 -= 3;
      gload_lds16(xq + aRowOff + (ks2 << 6), ldsA + (b2 << 13) + wave * 1024);
      gload_lds16(cq + (size_t)((kt2 << 7) + rowS) * DIM + (ks2 << 6) + offS,
                  ldsB + (b2 << 13) + wave * 1024);
      asm volatile("s_waitcnt vmcnt(4)" ::: "memory");   // 4 newest = steps j+1, j+2
    } else if (j + 2 == NSTEP) {
      asm volatile("s_waitcnt vmcnt(2)" ::: "memory");
    } else {
      asm volatile("s_waitcnt vmcnt(0)" ::: "memory");
    }
    __builtin_amdgcn_s_barrier();           // buf[bi] complete for all waves
    __builtin_amdgcn_sched_barrier(0);

    const unsigned char* A = ldsA + (bi << 13);
    const unsigned char* B = ldsB + (bi << 13);
    intx8 aF, bF[2];
    {
      int s0 = wm * 128 + fragSlotBase;
      intx4 lo = *(const intx4*)(A + s0 * 16);
      intx4 hi = *(const intx4*)(A + (s0 ^ 1) * 16);
      aF = (intx8){lo[0], lo[1], lo[2], lo[3], hi[0], hi[1], hi[2], hi[3]};
    }
#pragma unroll
    for (int fn = 0; fn < 2; ++fn) {
      int s0 = (wn * 2 + fn) * 128 + fragSlotBase;
      intx4 lo = *(const intx4*)(B + s0 * 16);
      intx4 hi = *(const intx4*)(B + (s0 ^ 1) * 16);
      bF[fn] = (intx8){lo[0], lo[1], lo[2], lo[3], hi[0], hi[1], hi[2], hi[3]};
    }
    asm volatile("s_waitcnt lgkmcnt(0)" ::: "memory");
    __builtin_amdgcn_sched_barrier(0);
#pragma unroll
    for (int fn = 0; fn < 2; ++fn)
      acc[fn] = __builtin_amdgcn_mfma_scale_f32_32x32x64_f8f6f4(
          aF, bF[fn], acc[fn], 0, 0, 0, SCALE1, 0, SCALE1);

    if (ks == KSTEPS - 1) {
      // ---- per-kt epilogue: s = ||c||^2_exact - 2*cross ----
      const int ktBase = kt << 7;
      float cs[2];
#pragma unroll
      for (int fn = 0; fn < 2; ++fn)
        cs[fn] = csqL[ktBase + wn * 64 + fn * 32 + l31];

      // tighten running min (shfl-reduce over the 32 cols)
#pragma unroll
      for (int r = 0; r < 16; ++r) {
        float v = fminf(cs[0] - 2.f * acc[0][r], cs[1] - 2.f * acc[1][r]);
        v = fminf(v, __shfl_xor(v, 1, 64));
        v = fminf(v, __shfl_xor(v, 2, 64));
        v = fminf(v, __shfl_xor(v, 4, 64));
        v = fminf(v, __shfl_xor(v, 8, 64));
        v = fminf(v, __shfl_xor(v, 16, 64));
        if (l31 == 0) {
          int srow = wm * 32 + (r & 3) + 8 * (r >> 2) + 4 * half;
          atomicMin(&sminU[srow], mapF(v));
        }
      }
      FENCE_BAR();

      // collect against tightened (prefix => superset) threshold
#pragma unroll
      for (int r = 0; r < 16; ++r) {
        int srow = wm * 32 + (r & 3) + 8 * (r >> 2) + 4 * half;
        float thr = unmapF(sminU[srow]) + MARGIN;
#pragma unroll
        for (int fn = 0; fn < 2; ++fn) {
          float s = cs[fn] - 2.f * acc[fn][r];
          if (s <= thr) {
            int k = ktBase + wn * 64 + fn * 32 + l31;
            int idx = atomicAdd(&candCount, 1);
            if (idx < CAND_CAP) {
              candKey[idx] = ((unsigned)k << 7) | (unsigned)srow;
              candS[idx] = s;
            }
          }
        }
      }
      FENCE_BAR();   // doubles as close barrier for buf[bi]

      // compaction backstop (rare; block-uniform branch)
      if (candCount > COMPACT_TRIG) {
        int cc = candCount; if (cc > CAND_CAP) cc = CAND_CAP;
        unsigned myK[4]; float myS[4]; int myN = 0;
        for (int i = t; i < cc; i += THREADS) {
          int rl = candKey[i] & 127;
          if (candS[i] <= unmapF(sminU[rl]) + MARGIN && myN < 4) {
            myK[myN] = candKey[i]; myS[myN] = candS[i]; ++myN;
          }
        }
        FENCE_BAR();
        if (t == 0) candCount = 0;
        FENCE_BAR();
        int base = atomicAdd(&candCount, myN);
        for (int jj = 0; jj < myN; ++jj) { candKey[base + jj] = myK[jj]; candS[base + jj] = myS[jj]; }
        FENCE_BAR();
      }

      // reset acc for next kt
#pragma unroll
      for (int fn = 0; fn < 2; ++fn)
#pragma unroll
        for (int e = 0; e < 16; ++e) acc[fn][e] = 0.f;
    } else {
      __builtin_amdgcn_s_barrier();   // close: all waves done reading buf[bi]
      __builtin_amdgcn_sched_barrier(0);
    }
    ++bi; if (bi == 3) bi = 0;
  }

  __syncthreads();  // pipeline drained (vmcnt 0); safe to use normal sync now

  // ---- fp64-exact refinement of surviving candidates (original fp32 inputs)
  int cnt = candCount; if (cnt > CAND_CAP) cnt = CAND_CAP;
  const int g = t >> 4;
  const int sl = t & 15;
  for (int ci = g; ci < cnt; ci += 32) {
    unsigned cd = candKey[ci];
    int rl = cd & 127;
    if (candS[ci] > unmapF(sminU[rl]) + MARGIN) continue;  // group-uniform branch
    int k = cd >> 7;
    const float* xr = x + (size_t)(rowBlock + rl) * DIM;
    const float* cr = cent + (size_t)k * DIM;
    double d = 0.0;
#pragma unroll
    for (int jj = 0; jj < DIM / 64; ++jj) {
      floatx4 xv = *(const floatx4*)(xr + jj * 64 + sl * 4);
      floatx4 cv = *(const floatx4*)(cr + jj * 64 + sl * 4);
#pragma unroll
      for (int e = 0; e < 4; ++e) {
        double df = (double)xv[e] - (double)cv[e];
        d += df * df;
      }
    }
#pragma unroll
    for (int off = 1; off < 16; off <<= 1) d += __shfl_xor(d, off, 64);
    if (sl == 0) {
      unsigned long long key =
          ((unsigned long long)__double_as_longlong(d) & ~0xFFFull) | (unsigned long long)k;
      atomicMin(&best[rl], key);
    }
  }
  __syncthreads();
  if (t < TILE_M) out[rowBlock + t] = (int)(best[t] & 0xFFFull);
}

// Fallback (no workspace): previous-generation kernel, fp32 loads + in-kernel
// fp8 convert, __syncthreads-based. Never used when ws is provided.
__global__ __launch_bounds__(THREADS, 4)
void kmeans_argmin_fb(const float* __restrict__ x, const float* __restrict__ cent,
                      int* __restrict__ out) {
  __shared__ unsigned char ldsA[TILE_M * BK];
  __shared__ unsigned char ldsB[TILE_N * BK];
  __shared__ float csq4[TILE_N][4];
  __shared__ unsigned sminU[TILE_M];
  __shared__ unsigned long long best[TILE_M];
  __shared__ unsigned candKey[CAND_CAP];
  __shared__ float candS[CAND_CAP];
  __shared__ int candCount;

  const int t = threadIdx.x;
  const int lane = t & 63;
  const int wave = t >> 6;
  const int wm = wave >> 1;
  const int wn = wave & 1;
  const int l31 = lane & 31;
  const int half = lane >> 5;
  const int rowBlock = blockIdx.x * TILE_M;

  if (t < TILE_M) { sminU[t] = 0xFFFFFFFFu; best[t] = ~0ull; }
  if (t == 0) candCount = 0;

  const int rS = (t >> 2) & 31;
  const int rowS = (t >> 7) * 32 + rS;
  const int offS = (((t & 3) ^ ((rS >> 1) & 3)) << 4);
  const int qk = half * 2;
  const int fragSlotBase = 4 * l31 + (qk ^ ((l31 >> 1) & 3));

  for (int kt = 0; kt < NKT; ++kt) {
    const int ktBase = kt * TILE_N;
    ((float*)csq4)[t] = 0.f;
    floatx16 acc[2];
#pragma unroll
    for (int fn = 0; fn < 2; ++fn)
#pragma unroll
      for (int e = 0; e < 16; ++e) acc[fn][e] = 0.f;

    for (int ks = 0; ks < KSTEPS; ++ks) {
      const int kd = ks * BK;
      {
        const float* gA = x + (size_t)(rowBlock + rowS) * DIM + kd + offS;
        floatx4 f0 = *(const floatx4*)gA, f1 = *(const floatx4*)(gA + 4);
        floatx4 f2 = *(const floatx4*)(gA + 8), f3 = *(const floatx4*)(gA + 12);
        intx4 q = { pk4(f0[0],f0[1],f0[2],f0[3]), pk4(f1[0],f1[1],f1[2],f1[3]),
                    pk4(f2[0],f2[1],f2[2],f2[3]), pk4(f3[0],f3[1],f3[2],f3[3]) };
        *(intx4*)(ldsA + (size_t)t * 16) = q;
      }
      {
        const float* gB = cent + (size_t)(ktBase + rowS) * DIM + kd + offS;
        floatx4 f0 = *(const floatx4*)gB, f1 = *(const floatx4*)(gB + 4);
        floatx4 f2 = *(const floatx4*)(gB + 8), f3 = *(const floatx4*)(gB + 12);
        intx4 q = { pk4(f0[0],f0[1],f0[2],f0[3]), pk4(f1[0],f1[1],f1[2],f1[3]),
                    pk4(f2[0],f2[1],f2[2],f2[3]), pk4(f3[0],f3[1],f3[2],f3[3]) };
        *(intx4*)(ldsB + (size_t)t * 16) = q;
        float s = 0.f;
#pragma unroll
        for (int e = 0; e < 4; ++e)
          s += f0[e]*f0[e] + f1[e]*f1[e] + f2[e]*f2[e] + f3[e]*f3[e];
        csq4[rowS][t & 3] += s;
      }
      __syncthreads();

      intx8 aF, bF[2];
      {
        int s0 = wm * 128 + fragSlotBase;
        intx4 lo = *(const intx4*)(ldsA + s0 * 16);
        intx4 hi = *(const intx4*)(ldsA + (s0 ^ 1) * 16);
        aF = (intx8){lo[0], lo[1], lo[2], lo[3], hi[0], hi[1], hi[2], hi[3]};
      }
#pragma unroll
      for (int fn = 0; fn < 2; ++fn) {
        int s0 = (wn * 2 + fn) * 128 + fragSlotBase;
        intx4 lo = *(const intx4*)(ldsB + s0 * 16);
        intx4 hi = *(const intx4*)(ldsB + (s0 ^ 1) * 16);
        bF[fn] = (intx8){lo[0], lo[1], lo[2], lo[3], hi[0], hi[1], hi[2], hi[3]};
      }
#pragma unroll
      for (int fn = 0; fn < 2; ++fn)
        acc[fn] = __builtin_amdgcn_mfma_scale_f32_32x32x64_f8f6f4(
            aF, bF[fn], acc[fn], 0, 0, 0, SCALE1, 0, SCALE1);
      __syncthreads();
    }

    float cs[2];
#pragma unroll
    for (int fn = 0; fn < 2; ++fn) {
      int cl = wn * 64 + fn * 32 + l31;
      cs[fn] = csq4[cl][0] + csq4[cl][1] + csq4[cl][2] + csq4[cl][3];
    }

#pragma unroll
    for (int r = 0; r < 16; ++r) {
      float v = fminf(cs[0] - 2.f * acc[0][r], cs[1] - 2.f * acc[1][r]);
      v = fminf(v, __shfl_xor(v, 1, 64));
      v = fminf(v, __shfl_xor(v, 2, 64));
      v = fminf(v, __shfl_xor(v, 4, 64));
      v = fminf(v, __shfl_xor(v, 8, 64));
      v = fminf(v, __shfl_xor(v, 16, 64));
      if (l31 == 0) {
        int srow = wm * 32 + (r & 3) + 8 * (r >> 2) + 4 * half;
        atomicMin(&sminU[srow], mapF(v));
      }
    }
    __syncthreads();

#pragma unroll
    for (int r = 0; r < 16; ++r) {
      int srow = wm * 32 + (r & 3) + 8 * (r >> 2) + 4 * half;
      float thr = unmapF(sminU[srow]) + MARGIN;
#pragma unroll
      for (int fn = 0; fn < 2; ++fn) {
        float s = cs[fn] - 2.f * acc[fn][r];
        if (s <= thr) {
          int k = ktBase + wn * 64 + fn * 32 + l31;
          int idx = atomicAdd(&candCount, 1);
          if (idx < CAND_CAP) {
            candKey[idx] = ((unsigned)k << 7) | (unsigned)srow;
            candS[idx] = s;
          }
        }
      }
    }
    __syncthreads();

    if (candCount > COMPACT_TRIG) {
      int cc = candCount; if (cc > CAND_CAP) cc = CAND_CAP;
      unsigned myK[4]; float myS[4]; int myN = 0;
      for (int i = t; i < cc; i += THREADS) {
        int rl = candKey[i] & 127;
        if (candS[i] <= unmapF(sminU[rl]) + MARGIN && myN < 4) {
          myK[myN] = candKey[i]; myS[myN] = candS[i]; ++myN;
        }
      }
      __syncthreads();
      if (t == 0) candCount = 0;
      __syncthreads();
      int base = atomicAdd(&candCount, myN);
      for (int j = 0; j < myN; ++j) { candKey[base + j] = myK[j]; candS[base + j] = myS[j]; }
      __syncthreads();
    }
  }

  int cnt = candCount; if (cnt > CAND_CAP) cnt = CAND_CAP;
  const int g = t >> 4;
  const int sl = t & 15;
  for (int ci = g; ci < cnt; ci += 32) {
    unsigned cd = candKey[ci];
    int rl = cd & 127;
    if (candS[ci] > unmapF(sminU[rl]) + MARGIN) continue;
    int k = cd >> 7;
    const float* xr = x + (size_t)(rowBlock + rl) * DIM;
    const float* cr = cent + (size_t)k * DIM;
    double d = 0.0;
#pragma unroll
    for (int j = 0; j < DIM / 64; ++j) {
      floatx4 xv = *(const floatx4*)(xr + j * 64 + sl * 4);
      floatx4 cv = *(const floatx4*)(cr + j * 64 + sl * 4);
#pragma unroll
      for (int e = 0; e < 4; ++e) {
        double df = (double)xv[e] - (double)cv[e];
        d += df * df;
      }
    }
#pragma unroll
    for (int off = 1; off < 16; off <<= 1) d += __shfl_xor(d, off, 64);
    if (sl == 0) {
      unsigned long long key =
          ((unsigned long long)__double_as_longlong(d) & ~0xFFFull) | (unsigned long long)k;
      atomicMin(&best[rl], key);
    }
  }
  __syncthreads();
  if (t < TILE_M) out[rowBlock + t] = (int)(best[t] & 0xFFFull);
}

extern "C" void kernel_launch(void* const* d_in, const int* in_sizes, int n_in,
                              void* d_out, int out_size, void* d_ws, size_t ws_size,
                              hipStream_t stream) {
  const float* x = (const float*)d_in[0];
  const float* cent = (const float*)d_in[1];
  int* out = (int*)d_out;
  const size_t nXq = (size_t)N_ROWS * DIM;          // 32 MiB fp8
  const size_t nCq = (size_t)K_CENT * DIM;          // 2 MiB fp8
  const size_t nCsq = (size_t)K_CENT * sizeof(float);
  const int grid = N_ROWS / TILE_M;                 // 512 blocks

  if (ws_size >= nXq + nCq + nCsq) {
    unsigned char* xq = (unsigned char*)d_ws;
    unsigned char* cq = xq + nXq;
    float* csqg = (float*)(cq + nCq);
    const size_t total16 = ((size_t)N_ROWS + K_CENT) * DIM / 16;
    prep_convert<<<(unsigned)((total16 + 255) / 256), 256, 0, stream>>>(x, cent, xq, cq, csqg);
    kmeans_argmin_pipe<<<grid, THREADS, 6 * 8192, stream>>>(x, cent, xq, cq, csqg, out);
  } else {
    kmeans_argmin_fb<<<grid, THREADS, 0, stream>>>(x, cent, out);
  }
}

// Round 2
// 601.871 us; speedup vs baseline: 1.0407x; 1.0361x over previous
//
#include <hip/hip_runtime.h>

#define N_ROWS 65536
#define DIM    512
#define K_CENT 4096
#define TILE_M 128
#define TILE_N 128
#define BK     64
#define KSTEPS (DIM / BK)        // 8
#define NKT    (K_CENT / TILE_N) // 32
#define THREADS 512
#define MARGIN 22.0f
#define CAND_CAP 1536
#define COMPACT_TRIG 1024
#define SCALE1 0x7F7F7F7F        // e8m0 scale = 2^0 in every byte

typedef float  floatx4  __attribute__((ext_vector_type(4)));
typedef float  floatx16 __attribute__((ext_vector_type(16)));
typedef int    intx2    __attribute__((ext_vector_type(2)));
typedef int    intx4    __attribute__((ext_vector_type(4)));
typedef int    intx8    __attribute__((ext_vector_type(8)));

// order-preserving float<->uint map
__device__ __forceinline__ unsigned mapF(float f) {
  unsigned u = __float_as_uint(f);
  return (u & 0x80000000u) ? ~u : (u | 0x80000000u);
}
__device__ __forceinline__ float unmapF(unsigned m) {
  unsigned u = (m & 0x80000000u) ? (m ^ 0x80000000u) : ~m;
  return __uint_as_float(u);
}

__device__ __forceinline__ void gload_lds16(const void* g, void* l) {
  __builtin_amdgcn_global_load_lds(
      (const __attribute__((address_space(1))) void*)g,
      (__attribute__((address_space(3))) void*)l, 16, 0, 0);
}

// pack 4 floats -> 4 OCP e4m3 bytes (byte order matches memory layout)
__device__ __forceinline__ int pk4(float a, float b, float c, float d) {
  int r = __builtin_amdgcn_cvt_pk_fp8_f32(a, b, 0, false);
  r = __builtin_amdgcn_cvt_pk_fp8_f32(c, d, r, true);
  return r;
}

// LDS-visibility barrier, NO vmcnt drain (prefetch stays in flight)
#define FENCE_BAR() do { asm volatile("s_waitcnt lgkmcnt(0)" ::: "memory"); \
                         __builtin_amdgcn_s_barrier();                       \
                         __builtin_amdgcn_sched_barrier(0); } while (0)

// Centers only: fp32 -> fp8 (16 elems/thread) + EXACT fp32 csq per row.
// x conversion is fused into the main kernel (x-frags live in registers).
__global__ void prep_convert(const float* __restrict__ c,
                             unsigned char* __restrict__ cq, float* __restrict__ csqg) {
  size_t i = ((size_t)blockIdx.x * blockDim.x + threadIdx.x) * 16;
  if (i >= (size_t)K_CENT * DIM) return;
  floatx4 a0 = *(const floatx4*)(c + i);
  floatx4 a1 = *(const floatx4*)(c + i + 4);
  floatx4 a2 = *(const floatx4*)(c + i + 8);
  floatx4 a3 = *(const floatx4*)(c + i + 12);
  intx4 q = { pk4(a0[0],a0[1],a0[2],a0[3]), pk4(a1[0],a1[1],a1[2],a1[3]),
              pk4(a2[0],a2[1],a2[2],a2[3]), pk4(a3[0],a3[1],a3[2],a3[3]) };
  *(intx4*)(cq + i) = q;
  float s = 0.f;
#pragma unroll
  for (int e = 0; e < 4; ++e)
    s += a0[e]*a0[e] + a1[e]*a1[e] + a2[e]*a2[e] + a3[e]*a3[e];
#pragma unroll
  for (int o = 1; o < 32; o <<= 1) s += __shfl_xor(s, o, 64);
  if ((threadIdx.x & 31) == 0) csqg[i >> 9] = s;  // 32 threads cover one 512-elem row
}

// Main kernel (R2 restructure):
//  - OPERAND SWAP: acc = mfma(centFrag, xFrag) -> C col (lane&31) = x-row,
//    C reg r = center (r&3)+8*(r>>2)+4*half. Per-x-row min over centers is
//    IN-LANE (31 fmin + 1 shfl_xor(32)), replacing 80 shfl/wave/kt.
//  - x IN REGISTERS: wave's x-frags invariant over kt -> convert fp32->fp8
//    once into xf[8] (64 VGPR). No A staging, no A ds_reads.
//  - 4-buf B ring, 1 gload_lds/thread/step, counted vmcnt(2), ONE barrier
//    per step (overwrite of buf b issued >=2 barriers after its reads).
//  - unrolled 8 steps/kt: buffer indices & ds_read offsets compile-time.
//  - wrapped tail prefetch reads garbage inside ws (cq + <2.3MB, ws ~36MB).
// VGPR budget: xf 64 + acc 32 + frag ptrs 4 + bOff 1 + transients ~20 < 128
// (launch_bounds (512,4) -> cap 128 for 2 blocks/CU; grid 512 = 2/CU).
__global__ __launch_bounds__(THREADS, 4)
void kmeans_argmin_pipe(const float* __restrict__ x, const float* __restrict__ cent,
                        const unsigned char* __restrict__ cq,
                        const float* __restrict__ csqg, int* __restrict__ out) {
  extern __shared__ __align__(16) unsigned char dynLds[];   // 4 * 8192 B ring
  __shared__ float csqL[K_CENT];              // 16 KB
  __shared__ unsigned sminU[TILE_M];
  __shared__ unsigned long long best[TILE_M];
  __shared__ unsigned candKey[CAND_CAP];      // 6 KB
  __shared__ float candS[CAND_CAP];           // 6 KB
  __shared__ int candCount;

  const int t = threadIdx.x;
  const int lane = t & 63;
  const int wave = t >> 6;   // 0..7
  const int wm = wave >> 1;  // 0..3 row-waves (32 x-rows each)
  const int wn = wave & 1;   // 0..1 col-waves (64 centers each)
  const int l31 = lane & 31;
  const int half = lane >> 5;
  const int rowBlock = blockIdx.x * TILE_M;
  const int srow = wm * 32 + l31;            // my x-row (C-layout col = lane&31)

  if (t < TILE_M) { sminU[t] = 0xFFFFFFFFu; best[t] = ~0ull; }
  if (t == 0) candCount = 0;
#pragma unroll
  for (int i = 0; i < K_CENT / THREADS; ++i) {
    int idx = t + i * THREADS;
    csqL[idx] = csqg[idx];
  }

  // B staging slot decode: thread t stages 16B at LDS slot t; slot holds
  // row rowS, byte-chunk offS of the 64B row (xor-swizzled for b128 reads)
  const int rS = (t >> 2) & 31;
  const int rowS = (t >> 7) * 32 + rS;
  const int offS = (((t & 3) ^ ((rS >> 1) & 3)) << 4);
  unsigned bOff = (unsigned)(rowS * DIM + offS);   // cq byte offset at step 0

  // frag read addresses (per lane, buffer offset added as compile-time imm)
  const int qk = half * 2;
  const int fragSlotBase = 4 * l31 + (qk ^ ((l31 >> 1) & 3));
  const unsigned char* pB0  = dynLds + (((wn * 2 + 0) * 128 + fragSlotBase) * 16);
  const unsigned char* pB0x = dynLds + ((((wn * 2 + 0) * 128 + fragSlotBase) ^ 1) * 16);
  const unsigned char* pB1  = dynLds + (((wn * 2 + 1) * 128 + fragSlotBase) * 16);
  const unsigned char* pB1x = dynLds + ((((wn * 2 + 1) * 128 + fragSlotBase) ^ 1) * 16);

  // ---- x -> fp8 fragments in registers (one-time). B-operand layout:
  // lane&31 = x-row-in-group, lane>>5 = k-half: bytes ks*64 + half*32 .. +31
  intx8 xf[KSTEPS];
  {
    const float* xr = x + (size_t)(rowBlock + srow) * DIM + half * 32;
#pragma unroll
    for (int ks = 0; ks < KSTEPS; ++ks) {
      int q[8];
#pragma unroll
      for (int j = 0; j < 8; ++j) {
        floatx4 f = *(const floatx4*)(xr + ks * 64 + j * 4);
        q[j] = pk4(f[0], f[1], f[2], f[3]);
      }
      xf[ks] = (intx8){q[0], q[1], q[2], q[3], q[4], q[5], q[6], q[7]};
    }
  }

  // retire all pre-loop vmem so loop vmcnt counting is exact
  asm volatile("s_waitcnt vmcnt(0)" ::: "memory");
  // prologue prefetch: steps 0,1 into bufs 0,1 (1 gload_lds per thread each)
  gload_lds16(cq + bOff, dynLds + 0 * 8192 + wave * 1024); bOff += 64;
  gload_lds16(cq + bOff, dynLds + 1 * 8192 + wave * 1024); bOff += 64;
  FENCE_BAR();   // csqL/sminU init visible; prefetch stays in flight

  for (int kt = 0; kt < NKT; ++kt) {
    floatx16 acc[2];
#pragma unroll
    for (int fn = 0; fn < 2; ++fn)
#pragma unroll
      for (int e = 0; e < 16; ++e) acc[fn][e] = 0.f;

#pragma unroll
    for (int p = 0; p < KSTEPS; ++p) {
      // issue prefetch for step j+2 (wraps harmlessly past the end: reads
      // garbage within ws into a buffer never consumed again)
      gload_lds16(cq + bOff, dynLds + (((p + 2) & 3) << 13) + wave * 1024);
      bOff += (p == 5) ? (65536 - 7 * 64) : 64;   // ks2==7 -> next kt row-block
      asm volatile("s_waitcnt vmcnt(2)" ::: "memory");   // step j's loads landed
      __builtin_amdgcn_s_barrier();                      // ...for ALL waves
      __builtin_amdgcn_sched_barrier(0);

      const int bo = (p & 3) << 13;   // compile-time buffer byte offset
      intx4 lo0 = *(const intx4*)(pB0  + bo);
      intx4 hi0 = *(const intx4*)(pB0x + bo);
      intx4 lo1 = *(const intx4*)(pB1  + bo);
      intx4 hi1 = *(const intx4*)(pB1x + bo);
      asm volatile("s_waitcnt lgkmcnt(0)" ::: "memory");
      __builtin_amdgcn_sched_barrier(0);
      intx8 b0 = (intx8){lo0[0], lo0[1], lo0[2], lo0[3], hi0[0], hi0[1], hi0[2], hi0[3]};
      intx8 b1 = (intx8){lo1[0], lo1[1], lo1[2], lo1[3], hi1[0], hi1[1], hi1[2], hi1[3]};
      // SWAPPED operands: centers = A (rows), x = B (cols)
      acc[0] = __builtin_amdgcn_mfma_scale_f32_32x32x64_f8f6f4(
          b0, xf[p], acc[0], 0, 0, 0, SCALE1, 0, SCALE1);
      acc[1] = __builtin_amdgcn_mfma_scale_f32_32x32x64_f8f6f4(
          b1, xf[p], acc[1], 0, 0, 0, SCALE1, 0, SCALE1);
    }

    // ---- epilogue: s(center k) = csq[k] - 2*cross  (||x||^2 const per row)
    // acc[fn][4g+e] is center k = kt*128 + (wn*2+fn)*32 + 8g + 4*half + e,
    // all for x-row srow. Min over my 32 values is pure in-lane VALU.
    const int ktBase = kt << 7;
    float mn = 3.4e38f;
#pragma unroll
    for (int fn = 0; fn < 2; ++fn)
#pragma unroll
      for (int g = 0; g < 4; ++g) {
        floatx4 cs4 = *(const floatx4*)&csqL[ktBase + (wn * 2 + fn) * 32 + 8 * g + 4 * half];
#pragma unroll
        for (int e = 0; e < 4; ++e)
          mn = fminf(mn, cs4[e] - 2.f * acc[fn][4 * g + e]);
      }
    mn = fminf(mn, __shfl_xor(mn, 32, 64));   // combine the two center-halves
    if (half == 0) atomicMin(&sminU[srow], mapF(mn));
    FENCE_BAR();

    // collect against the tightened (prefix => superset) threshold
    {
      float thr = unmapF(sminU[srow]) + MARGIN;
#pragma unroll
      for (int fn = 0; fn < 2; ++fn)
#pragma unroll
        for (int g = 0; g < 4; ++g) {
          floatx4 cs4 = *(const floatx4*)&csqL[ktBase + (wn * 2 + fn) * 32 + 8 * g + 4 * half];
#pragma unroll
          for (int e = 0; e < 4; ++e) {
            float s = cs4[e] - 2.f * acc[fn][4 * g + e];
            if (s <= thr) {
              int k = ktBase + (wn * 2 + fn) * 32 + 8 * g + 4 * half + e;
              int idx = atomicAdd(&candCount, 1);
              if (idx < CAND_CAP) {
                candKey[idx] = ((unsigned)k << 7) | (unsigned)srow;
                candS[idx] = s;
              }
            }
          }
        }
    }
    FENCE_BAR();

    // compaction backstop (rare; block-uniform branch)
    if (candCount > COMPACT_TRIG) {
      int cc = candCount; if (cc > CAND_CAP) cc = CAND_CAP;
      unsigned myK[4]; float myS[4]; int myN = 0;
      for (int i = t; i < cc; i += THREADS) {
        int rl = candKey[i] & 127;
        if (candS[i] <= unmapF(sminU[rl]) + MARGIN && myN < 4) {
          myK[myN] = candKey[i]; myS[myN] = candS[i]; ++myN;
        }
      }
      FENCE_BAR();
      if (t == 0) candCount = 0;
      FENCE_BAR();
      int base = atomicAdd(&candCount, myN);
      for (int jj = 0; jj < myN; ++jj) { candKey[base + jj] = myK[jj]; candS[base + jj] = myS[jj]; }
      FENCE_BAR();
    }
  }

  __syncthreads();  // full drain (incl. wrapped tail prefetches)

  // ---- fp64-exact refinement of surviving candidates (original fp32 inputs)
  int cnt = candCount; if (cnt > CAND_CAP) cnt = CAND_CAP;
  const int g = t >> 4;   // 32 groups of 16 lanes
  const int sl = t & 15;
  for (int ci = g; ci < cnt; ci += 32) {
    unsigned cd = candKey[ci];
    int rl = cd & 127;
    if (candS[ci] > unmapF(sminU[rl]) + MARGIN) continue;  // group-uniform branch
    int k = cd >> 7;
    const float* xr = x + (size_t)(rowBlock + rl) * DIM;
    const float* cr = cent + (size_t)k * DIM;
    double d = 0.0;
#pragma unroll
    for (int jj = 0; jj < DIM / 64; ++jj) {
      floatx4 xv = *(const floatx4*)(xr + jj * 64 + sl * 4);
      floatx4 cv = *(const floatx4*)(cr + jj * 64 + sl * 4);
#pragma unroll
      for (int e = 0; e < 4; ++e) {
        double df = (double)xv[e] - (double)cv[e];
        d += df * df;
      }
    }
#pragma unroll
    for (int off = 1; off < 16; off <<= 1) d += __shfl_xor(d, off, 64);
    if (sl == 0) {
      // positive doubles order as uint64; low 12 mantissa bits -> index (ties: lower k)
      unsigned long long key =
          ((unsigned long long)__double_as_longlong(d) & ~0xFFFull) | (unsigned long long)k;
      atomicMin(&best[rl], key);
    }
  }
  __syncthreads();
  if (t < TILE_M) out[rowBlock + t] = (int)(best[t] & 0xFFFull);
}

// Fallback (no workspace): previous-generation self-contained kernel.
__global__ __launch_bounds__(THREADS, 4)
void kmeans_argmin_fb(const float* __restrict__ x, const float* __restrict__ cent,
                      int* __restrict__ out) {
  __shared__ unsigned char ldsA[TILE_M * BK];
  __shared__ unsigned char ldsB[TILE_N * BK];
  __shared__ float csq4[TILE_N][4];
  __shared__ unsigned sminU[TILE_M];
  __shared__ unsigned long long best[TILE_M];
  __shared__ unsigned candKey[CAND_CAP];
  __shared__ float candS[CAND_CAP];
  __shared__ int candCount;

  const int t = threadIdx.x;
  const int lane = t & 63;
  const int wave = t >> 6;
  const int wm = wave >> 1;
  const int wn = wave & 1;
  const int l31 = lane & 31;
  const int half = lane >> 5;
  const int rowBlock = blockIdx.x * TILE_M;

  if (t < TILE_M) { sminU[t] = 0xFFFFFFFFu; best[t] = ~0ull; }
  if (t == 0) candCount = 0;

  const int rS = (t >> 2) & 31;
  const int rowS = (t >> 7) * 32 + rS;
  const int offS = (((t & 3) ^ ((rS >> 1) & 3)) << 4);
  const int qk = half * 2;
  const int fragSlotBase = 4 * l31 + (qk ^ ((l31 >> 1) & 3));

  for (int kt = 0; kt < NKT; ++kt) {
    const int ktBase = kt * TILE_N;
    ((float*)csq4)[t] = 0.f;
    floatx16 acc[2];
#pragma unroll
    for (int fn = 0; fn < 2; ++fn)
#pragma unroll
      for (int e = 0; e < 16; ++e) acc[fn][e] = 0.f;

    for (int ks = 0; ks < KSTEPS; ++ks) {
      const int kd = ks * BK;
      {
        const float* gA = x + (size_t)(rowBlock + rowS) * DIM + kd + offS;
        floatx4 f0 = *(const floatx4*)gA, f1 = *(const floatx4*)(gA + 4);
        floatx4 f2 = *(const floatx4*)(gA + 8), f3 = *(const floatx4*)(gA + 12);
        intx4 q = { pk4(f0[0],f0[1],f0[2],f0[3]), pk4(f1[0],f1[1],f1[2],f1[3]),
                    pk4(f2[0],f2[1],f2[2],f2[3]), pk4(f3[0],f3[1],f3[2],f3[3]) };
        *(intx4*)(ldsA + (size_t)t * 16) = q;
      }
      {
        const float* gB = cent + (size_t)(ktBase + rowS) * DIM + kd + offS;
        floatx4 f0 = *(const floatx4*)gB, f1 = *(const floatx4*)(gB + 4);
        floatx4 f2 = *(const floatx4*)(gB + 8), f3 = *(const floatx4*)(gB + 12);
        intx4 q = { pk4(f0[0],f0[1],f0[2],f0[3]), pk4(f1[0],f1[1],f1[2],f1[3]),
                    pk4(f2[0],f2[1],f2[2],f2[3]), pk4(f3[0],f3[1],f3[2],f3[3]) };
        *(intx4*)(ldsB + (size_t)t * 16) = q;
        float s = 0.f;
#pragma unroll
        for (int e = 0; e < 4; ++e)
          s += f0[e]*f0[e] + f1[e]*f1[e] + f2[e]*f2[e] + f3[e]*f3[e];
        csq4[rowS][t & 3] += s;
      }
      __syncthreads();

      intx8 aF, bF[2];
      {
        int s0 = wm * 128 + fragSlotBase;
        intx4 lo = *(const intx4*)(ldsA + s0 * 16);
        intx4 hi = *(const intx4*)(ldsA + (s0 ^ 1) * 16);
        aF = (intx8){lo[0], lo[1], lo[2], lo[3], hi[0], hi[1], hi[2], hi[3]};
      }
#pragma unroll
      for (int fn = 0; fn < 2; ++fn) {
        int s0 = (wn * 2 + fn) * 128 + fragSlotBase;
        intx4 lo = *(const intx4*)(ldsB + s0 * 16);
        intx4 hi = *(const intx4*)(ldsB + (s0 ^ 1) * 16);
        bF[fn] = (intx8){lo[0], lo[1], lo[2], lo[3], hi[0], hi[1], hi[2], hi[3]};
      }
#pragma unroll
      for (int fn = 0; fn < 2; ++fn)
        acc[fn] = __builtin_amdgcn_mfma_scale_f32_32x32x64_f8f6f4(
            aF, bF[fn], acc[fn], 0, 0, 0, SCALE1, 0, SCALE1);
      __syncthreads();
    }

    float cs[2];
#pragma unroll
    for (int fn = 0; fn < 2; ++fn) {
      int cl = wn * 64 + fn * 32 + l31;
      cs[fn] = csq4[cl][0] + csq4[cl][1] + csq4[cl][2] + csq4[cl][3];
    }

#pragma unroll
    for (int r = 0; r < 16; ++r) {
      float v = fminf(cs[0] - 2.f * acc[0][r], cs[1] - 2.f * acc[1][r]);
      v = fminf(v, __shfl_xor(v, 1, 64));
      v = fminf(v, __shfl_xor(v, 2, 64));
      v = fminf(v, __shfl_xor(v, 4, 64));
      v = fminf(v, __shfl_xor(v, 8, 64));
      v = fminf(v, __shfl_xor(v, 16, 64));
      if (l31 == 0) {
        int srow = wm * 32 + (r & 3) + 8 * (r >> 2) + 4 * half;
        atomicMin(&sminU[srow], mapF(v));
      }
    }
    __syncthreads();

#pragma unroll
    for (int r = 0; r < 16; ++r) {
      int srow = wm * 32 + (r & 3) + 8 * (r >> 2) + 4 * half;
      float thr = unmapF(sminU[srow]) + MARGIN;
#pragma unroll
      for (int fn = 0; fn < 2; ++fn) {
        float s = cs[fn] - 2.f * acc[fn][r];
        if (s <= thr) {
          int k = ktBase + wn * 64 + fn * 32 + l31;
          int idx = atomicAdd(&candCount, 1);
          if (idx < CAND_CAP) {
            candKey[idx] = ((unsigned)k << 7) | (unsigned)srow;
            candS[idx] = s;
          }
        }
      }
    }
    __syncthreads();

    if (candCount > COMPACT_TRIG) {
      int cc = candCount; if (cc > CAND_CAP) cc = CAND_CAP;
      unsigned myK[4]; float myS[4]; int myN = 0;
      for (int i = t; i < cc; i += THREADS) {
        int rl = candKey[i] & 127;
        if (candS[i] <= unmapF(sminU[rl]) + MARGIN && myN < 4) {
          myK[myN] = candKey[i]; myS[myN] = candS[i]; ++myN;
        }
      }
      __syncthreads();
      if (t == 0) candCount = 0;
      __syncthreads();
      int base = atomicAdd(&candCount, myN);
      for (int j = 0; j < myN; ++j) { candKey[base + j] = myK[j]; candS[base + j] = myS[j]; }
      __syncthreads();
    }
  }

  int cnt = candCount; if (cnt > CAND_CAP) cnt = CAND_CAP;
  const int g = t >> 4;
  const int sl = t & 15;
  for (int ci = g; ci < cnt; ci += 32) {
    unsigned cd = candKey[ci];
    int rl = cd & 127;
    if (candS[ci] > unmapF(sminU[rl]) + MARGIN) continue;
    int k = cd >> 7;
    const float* xr = x + (size_t)(rowBlock + rl) * DIM;
    const float* cr = cent + (size_t)k * DIM;
    double d = 0.0;
#pragma unroll
    for (int j = 0; j < DIM / 64; ++j) {
      floatx4 xv = *(const floatx4*)(xr + j * 64 + sl * 4);
      floatx4 cv = *(const floatx4*)(cr + j * 64 + sl * 4);
#pragma unroll
      for (int e = 0; e < 4; ++e) {
        double df = (double)xv[e] - (double)cv[e];
        d += df * df;
      }
    }
#pragma unroll
    for (int off = 1; off < 16; off <<= 1) d += __shfl_xor(d, off, 64);
    if (sl == 0) {
      unsigned long long key =
          ((unsigned long long)__double_as_longlong(d) & ~0xFFFull) | (unsigned long long)k;
      atomicMin(&best[rl], key);
    }
  }
  __syncthreads();
  if (t < TILE_M) out[rowBlock + t] = (int)(best[t] & 0xFFFull);
}

extern "C" void kernel_launch(void* const* d_in, const int* in_sizes, int n_in,
                              void* d_out, int out_size, void* d_ws, size_t ws_size,
                              hipStream_t stream) {
  const float* x = (const float*)d_in[0];
  const float* cent = (const float*)d_in[1];
  int* out = (int*)d_out;
  const size_t nXq = (size_t)N_ROWS * DIM;          // kept as ws-size gate (known-good)
  const size_t nCq = (size_t)K_CENT * DIM;          // 2 MiB fp8
  const size_t nCsq = (size_t)K_CENT * sizeof(float);
  const int grid = N_ROWS / TILE_M;                 // 512 blocks

  if (ws_size >= nXq + nCq + nCsq) {
    // layout: cq first, csq after; wrapped tail prefetches read < cq+2.3MB,
    // comfortably inside the >=36MB workspace.
    unsigned char* cq = (unsigned char*)d_ws;
    float* csqg = (float*)(cq + nCq);
    const size_t total16 = nCq / 16;
    prep_convert<<<(unsigned)((total16 + 255) / 256), 256, 0, stream>>>(cent, cq, csqg);
    kmeans_argmin_pipe<<<grid, THREADS, 4 * 8192, stream>>>(x, cent, cq, csqg, out);
  } else {
    kmeans_argmin_fb<<<grid, THREADS, 0, stream>>>(x, cent, out);
  }
}